// Round 10
// baseline (57450.043 us; speedup 1.0000x reference)
//
#include <hip/hip_runtime.h>

// Problem constants
#define T_SEQ   8192
#define N_RES   2048
#define K_IN    512

// Geometry: 64 blocks x 512 threads (8 waves); 32 rows/block, 4 rows/wave.
#define G_BLOCKS 64
#define B_THREADS 512
#define ROWS_PER_WAVE 4
#define ROWS_PER_BLOCK 32
static_assert(G_BLOCKS * ROWS_PER_BLOCK == N_RES, "row partition mismatch");

#define INV_SQRT_N 0.022097086912079612f

// Phase encoding: packet float e = phi*(v + ENC_OFF), phi alternates per ring
// generation (phi(g) = ((g>>1)&1) ? -1 : +1, slot = g&1). |v| <= 0.0222 so
// |e| in [0.078, 0.122]. Ready iff phi_expected*e > ENC_THR; stale (gen-2)
// packet has opposite phi -> not-ready; zero-init -> not-ready.
#define ENC_OFF 0.1f
#define ENC_THR 0.05f

// Swizzled ring slot for state-pair p (p = col/2): consumer lane l polls
// pairs 16l+i at slot i*64+l  ->  each poll load instr covers 512 contiguous
// bytes per wave (fully coalesced), unlike round 3's scattered 8B loads.
#define SLOT(p) ((((p) & 15) << 6) | ((p) >> 4))

typedef unsigned long long u64;
typedef unsigned int u32;
typedef float f32x2 __attribute__((ext_vector_type(2)));

__device__ __forceinline__ float fast_tanh(float v) {
    float e = __expf(2.0f * v);
    return 1.0f - 2.0f / (e + 1.0f);
}

#define KEEP2(v) asm("" : "+v"(v))

// d_ws layout: ring [2][1024] u64 (16 KB)
__global__ __launch_bounds__(B_THREADS, 2)
void reservoir_v10(const float* __restrict__ input,   // [T_SEQ][K_IN]
                   const float* __restrict__ state0,  // [N_RES]
                   const float* __restrict__ W_in,    // [N_RES][K_IN]
                   const float* __restrict__ W_res,   // [N_RES][N_RES]
                   float* __restrict__ out,           // [T_SEQ+1][N_RES]
                   u64* __restrict__ ring)
{
    const int tid  = threadIdx.x;
    const int lane = tid & 63;
    const int wave = tid >> 6;
    const int blk  = blockIdx.x;
    const int r0   = blk * ROWS_PER_BLOCK + wave * ROWS_PER_WAVE;

    // ---- weights: lane l owns W_res cols [32l, 32l+32) (matches ring pairs
    //      16l..16l+15); W_in keeps cols {4l+256i} (matches coalesced x loads).
    f32x2 wr2[ROWS_PER_WAVE][16];
    f32x2 wi2[ROWS_PER_WAVE][4];
    #pragma unroll
    for (int k = 0; k < ROWS_PER_WAVE; ++k) {
        const float* rrow = W_res + (size_t)(r0 + k) * N_RES + 32 * lane;
        #pragma unroll
        for (int i = 0; i < 8; ++i) {
            float4 w = *reinterpret_cast<const float4*>(rrow + 4 * i);
            wr2[k][2 * i]     = (f32x2){w.x, w.y};
            wr2[k][2 * i + 1] = (f32x2){w.z, w.w};
        }
        const float* irow = W_in + (size_t)(r0 + k) * K_IN;
        #pragma unroll
        for (int i = 0; i < 2; ++i) {
            float4 w = *reinterpret_cast<const float4*>(irow + 4 * lane + 256 * i);
            wi2[k][2 * i]     = (f32x2){w.x, w.y};
            wi2[k][2 * i + 1] = (f32x2){w.z, w.w};
        }
    }

    // out row 0 = initial state
    if (blk == 0)
        for (int j = tid; j < N_RES; j += B_THREADS) out[j] = state0[j];

    // x row 0 as packed pairs (layout matches wi cols {4l+256i})
    f32x2 xv[4];
    {
        float4 a = *reinterpret_cast<const float4*>(input + 4 * lane);
        float4 b = *reinterpret_cast<const float4*>(input + 4 * lane + 256);
        xv[0] = (f32x2){a.x, a.y}; xv[1] = (f32x2){a.z, a.w};
        xv[2] = (f32x2){b.x, b.y}; xv[3] = (f32x2){b.z, b.w};
    }

    for (int t = 0; t < T_SEQ; ++t) {
        // issue x_{t+1} prefetch before the spin so HBM latency hides under it
        f32x2 xn[4] = {xv[0], xv[1], xv[2], xv[3]};
        if (t + 1 < T_SEQ) {
            const float* xr = input + (size_t)(t + 1) * K_IN;
            float4 a = *reinterpret_cast<const float4*>(xr + 4 * lane);
            float4 b = *reinterpret_cast<const float4*>(xr + 4 * lane + 256);
            xn[0] = (f32x2){a.x, a.y}; xn[1] = (f32x2){a.z, a.w};
            xn[2] = (f32x2){b.x, b.y}; xn[3] = (f32x2){b.z, b.w};
        }

        // ---- input contribution (packed) ----
        f32x2 acc2[ROWS_PER_WAVE];
        #pragma unroll
        for (int k = 0; k < ROWS_PER_WAVE; ++k) {
            f32x2 a = (f32x2){0.0f, 0.0f};
            #pragma unroll
            for (int i = 0; i < 4; ++i)
                a = __builtin_elementwise_fma(wi2[k][i], xv[i], a);
            acc2[k] = a;
        }

        // ---- state contribution ----
        if (t == 0) {
            const float* sp = state0 + 32 * lane;
            #pragma unroll
            for (int i = 0; i < 8; ++i) {
                float4 s = *reinterpret_cast<const float4*>(sp + 4 * i);
                f32x2 s01 = (f32x2){s.x, s.y}, s23 = (f32x2){s.z, s.w};
                #pragma unroll
                for (int k = 0; k < ROWS_PER_WAVE; ++k) {
                    acc2[k] = __builtin_elementwise_fma(wr2[k][2 * i],     s01, acc2[k]);
                    acc2[k] = __builtin_elementwise_fma(wr2[k][2 * i + 1], s23, acc2[k]);
                }
            }
        } else {
            // ---- fused poll+FMA over this lane's 16 swizzled ring entries.
            // Gather loop first (16 independent loads pipeline into ~1 RT),
            // then process/FMA the arrived ones; repeat for stragglers.
            const float phi = ((t >> 1) & 1) ? -1.0f : 1.0f;
            const u64* rp = ring + ((t & 1) << 10) + lane;
            u32 pend = 0xFFFFu;
            while (pend) {
                u64 e[16];
                #pragma unroll
                for (int i = 0; i < 16; ++i)
                    if (pend & (1u << i))
                        e[i] = __hip_atomic_load(rp + 64 * i, __ATOMIC_RELAXED,
                                                 __HIP_MEMORY_SCOPE_AGENT);
                #pragma unroll
                for (int i = 0; i < 16; ++i) {
                    if (pend & (1u << i)) {
                        float lo = __uint_as_float((u32)e[i]);
                        float hi = __uint_as_float((u32)(e[i] >> 32));
                        if (phi * lo > ENC_THR && phi * hi > ENC_THR) {
                            f32x2 sv = {fmaf(phi, lo, -ENC_OFF),
                                        fmaf(phi, hi, -ENC_OFF)};
                            #pragma unroll
                            for (int k = 0; k < ROWS_PER_WAVE; ++k)
                                acc2[k] = __builtin_elementwise_fma(wr2[k][i], sv,
                                                                    acc2[k]);
                            pend &= ~(1u << i);
                        }
                    }
                }
                if (pend) __builtin_amdgcn_s_sleep(1);
            }
        }

        // ---- horizontal + full-wave butterfly reduce (4 rows in flight) ----
        float acc[ROWS_PER_WAVE];
        #pragma unroll
        for (int k = 0; k < ROWS_PER_WAVE; ++k) acc[k] = acc2[k].x + acc2[k].y;
        #pragma unroll
        for (int off = 32; off > 0; off >>= 1) {
            #pragma unroll
            for (int k = 0; k < ROWS_PER_WAVE; ++k)
                acc[k] += __shfl_xor(acc[k], off, 64);
        }

        // ---- finalize: publish to swizzled slots first, out store off-path ----
        const float v0 = fast_tanh(acc[0]) * INV_SQRT_N;
        const float v1 = fast_tanh(acc[1]) * INV_SQRT_N;
        const float v2 = fast_tanh(acc[2]) * INV_SQRT_N;
        const float v3 = fast_tanh(acc[3]) * INV_SQRT_N;
        const int   slotn = (t + 1) & 1;
        const float phin  = (((t + 1) >> 1) & 1) ? -1.0f : 1.0f;
        const int   p0    = r0 >> 1;
        if (lane == 0) {
            u64 pk = (u64)__float_as_uint(phin * (v0 + ENC_OFF)) |
                     ((u64)__float_as_uint(phin * (v1 + ENC_OFF)) << 32);
            __hip_atomic_store(ring + (slotn << 10) + SLOT(p0), pk,
                               __ATOMIC_RELAXED, __HIP_MEMORY_SCOPE_AGENT);
        } else if (lane == 1) {
            u64 pk = (u64)__float_as_uint(phin * (v2 + ENC_OFF)) |
                     ((u64)__float_as_uint(phin * (v3 + ENC_OFF)) << 32);
            __hip_atomic_store(ring + (slotn << 10) + SLOT(p0 + 1), pk,
                               __ATOMIC_RELAXED, __HIP_MEMORY_SCOPE_AGENT);
        } else if (lane == 2) {
            // per-wave out store (rows r0..r0+3) — lane-scoped
            *reinterpret_cast<float4*>(out + (size_t)(t + 1) * N_RES + r0) =
                make_float4(v0, v1, v2, v3);
        }

        // ---- pin weights across the back edge ----
        #pragma unroll
        for (int k = 0; k < ROWS_PER_WAVE; ++k) {
            #pragma unroll
            for (int i = 0; i < 16; ++i) KEEP2(wr2[k][i]);
            #pragma unroll
            for (int i = 0; i < 4; ++i)  KEEP2(wi2[k][i]);
        }

        #pragma unroll
        for (int i = 0; i < 4; ++i) xv[i] = xn[i];
    }
}

extern "C" void kernel_launch(void* const* d_in, const int* in_sizes, int n_in,
                              void* d_out, int out_size, void* d_ws, size_t ws_size,
                              hipStream_t stream) {
    const float* input  = (const float*)d_in[0];
    const float* state0 = (const float*)d_in[1];
    const float* W_in   = (const float*)d_in[2];
    const float* W_res  = (const float*)d_in[3];
    float* out = (float*)d_out;
    u64* ring  = (u64*)d_ws;

    // zero = "not ready" for both phases; re-cleared on every call/replay
    hipMemsetAsync(d_ws, 0, 2 * (N_RES / 2) * sizeof(u64), stream);

    void* args[] = { (void*)&input, (void*)&state0, (void*)&W_in, (void*)&W_res,
                     (void*)&out, (void*)&ring };
    hipLaunchCooperativeKernel((const void*)reservoir_v10,
                               dim3(G_BLOCKS), dim3(B_THREADS),
                               args, 0, stream);
}

// Round 11
// 16837.427 us; speedup vs baseline: 3.4120x; 3.4120x over previous
//
#include <hip/hip_runtime.h>

// Problem constants
#define T_SEQ   8192
#define N_RES   2048
#define K_IN    512

// Geometry: 64 blocks x 512 threads (8 waves); 32 rows/block, 4 rows/wave.
#define G_BLOCKS 64
#define B_THREADS 512
#define ROWS_PER_WAVE 4
#define ROWS_PER_BLOCK 32
static_assert(G_BLOCKS * ROWS_PER_BLOCK == N_RES, "row partition mismatch");

#define INV_SQRT_N 0.022097086912079612f

// Phase encoding: packet float e = phi*(v + ENC_OFF), phi alternates per ring
// generation (phi(g) = ((g>>1)&1) ? -1 : +1, slot = g&1). |v| <= 0.0222 so
// |e| in [0.078, 0.122]. Ready iff phi_expected*e > ENC_THR; stale (gen-2)
// packet has opposite phi -> not-ready; zero-init -> not-ready.
// Each 32-bit word is INDEPENDENTLY self-validating -> no packet atomicity
// needed -> 16B non-atomic coherent stores/loads are legal.
#define ENC_OFF 0.1f
#define ENC_THR 0.05f

typedef unsigned long long u64;
typedef unsigned int u32;
typedef float f32x2 __attribute__((ext_vector_type(2)));
typedef float f32x4 __attribute__((ext_vector_type(4)));

__device__ __forceinline__ float fast_tanh(float v) {
    float e = __expf(2.0f * v);
    return 1.0f - 2.0f / (e + 1.0f);
}

// Coherent 16B access at the agent coherence point: sc0 (bypass L1) +
// sc1 (bypass local-XCD L2) — same cache policy the compiler emits for
// agent-scope relaxed atomics, but 16B wide.
__device__ __forceinline__ void store_f4_coh(float* p, f32x4 v) {
    asm volatile("global_store_dwordx4 %0, %1, off sc0 sc1"
                 :: "v"(p), "v"(v) : "memory");
}
__device__ __forceinline__ f32x4 load_f4_coh(const float* p) {
    f32x4 r;
    asm volatile("global_load_dwordx4 %0, %1, off sc0 sc1\n\t"
                 "s_waitcnt vmcnt(0)"
                 : "=v"(r) : "v"(p) : "memory");
    return r;
}

#define KEEP2(v) asm("" : "+v"(v))

// d_ws layout: ring [2][2048] f32 (16 KB)
__global__ __launch_bounds__(B_THREADS, 2)
void reservoir_v11(const float* __restrict__ input,   // [T_SEQ][K_IN]
                   const float* __restrict__ state0,  // [N_RES]
                   const float* __restrict__ W_in,    // [N_RES][K_IN]
                   const float* __restrict__ W_res,   // [N_RES][N_RES]
                   float* __restrict__ out,           // [T_SEQ+1][N_RES]
                   float* __restrict__ ring)
{
    const int tid  = threadIdx.x;
    const int lane = tid & 63;
    const int wave = tid >> 6;
    const int blk  = blockIdx.x;
    const int r0   = blk * ROWS_PER_BLOCK + wave * ROWS_PER_WAVE;

    __shared__ float s_lds[2][N_RES];   // double-buffered state (16 KB)

    // ---- persistent weights as packed f32x2: lane l owns cols {4l+256i} ----
    f32x2 wr2[ROWS_PER_WAVE][16];   // W_res row k, 16 pairs = 32 cols
    f32x2 wi2[ROWS_PER_WAVE][4];    // W_in  row k, 4 pairs = 8 cols
    #pragma unroll
    for (int k = 0; k < ROWS_PER_WAVE; ++k) {
        const float* rrow = W_res + (size_t)(r0 + k) * N_RES;
        #pragma unroll
        for (int i = 0; i < 8; ++i) {
            float4 w = *reinterpret_cast<const float4*>(rrow + 4 * lane + 256 * i);
            wr2[k][2 * i]     = (f32x2){w.x, w.y};
            wr2[k][2 * i + 1] = (f32x2){w.z, w.w};
        }
        const float* irow = W_in + (size_t)(r0 + k) * K_IN;
        #pragma unroll
        for (int i = 0; i < 2; ++i) {
            float4 w = *reinterpret_cast<const float4*>(irow + 4 * lane + 256 * i);
            wi2[k][2 * i]     = (f32x2){w.x, w.y};
            wi2[k][2 * i + 1] = (f32x2){w.z, w.w};
        }
    }

    // out row 0 = initial state
    if (blk == 0)
        for (int j = tid; j < N_RES; j += B_THREADS) out[j] = state0[j];

    // s_0 -> LDS buffer 0 (covered by the in-loop __syncthreads at t=0)
    #pragma unroll
    for (int i = 0; i < 4; ++i)
        s_lds[0][i * 512 + tid] = state0[i * 512 + tid];

    // x row 0 as packed pairs (layout matches wi cols {4l+256i})
    f32x2 xv[4];
    {
        float4 a = *reinterpret_cast<const float4*>(input + 4 * lane);
        float4 b = *reinterpret_cast<const float4*>(input + 4 * lane + 256);
        xv[0] = (f32x2){a.x, a.y}; xv[1] = (f32x2){a.z, a.w};
        xv[2] = (f32x2){b.x, b.y}; xv[3] = (f32x2){b.z, b.w};
    }

    for (int t = 0; t < T_SEQ; ++t) {
        const int buf = t & 1;

        // issue x_{t+1} prefetch before the spin so HBM latency hides under it
        f32x2 xn[4] = {xv[0], xv[1], xv[2], xv[3]};
        if (t + 1 < T_SEQ) {
            const float* xr = input + (size_t)(t + 1) * K_IN;
            float4 a = *reinterpret_cast<const float4*>(xr + 4 * lane);
            float4 b = *reinterpret_cast<const float4*>(xr + 4 * lane + 256);
            xn[0] = (f32x2){a.x, a.y}; xn[1] = (f32x2){a.z, a.w};
            xn[2] = (f32x2){b.x, b.y}; xn[3] = (f32x2){b.z, b.w};
        }

        if (t > 0) {
            // ---- single-load poll: thread tid owns state cols [4tid, 4tid+4)
            // One 16B coherent load per round; wave footprint = 1KB contiguous.
            const float phi = ((t >> 1) & 1) ? -1.0f : 1.0f;
            const float* rp = ring + (buf << 11) + 4 * tid;
            f32x4 e;
            for (;;) {
                e = load_f4_coh(rp);
                if (phi * e.x > ENC_THR && phi * e.y > ENC_THR &&
                    phi * e.z > ENC_THR && phi * e.w > ENC_THR) break;
                __builtin_amdgcn_s_sleep(1);   // ~64cy backoff
            }
            float4 sv = make_float4(fmaf(phi, e.x, -ENC_OFF),
                                    fmaf(phi, e.y, -ENC_OFF),
                                    fmaf(phi, e.z, -ENC_OFF),
                                    fmaf(phi, e.w, -ENC_OFF));
            *reinterpret_cast<float4*>(&s_lds[buf][4 * tid]) = sv;
        }
        __syncthreads();

        // ---- state fragment from LDS as packed pairs ----
        f32x2 sp[16];
        #pragma unroll
        for (int i = 0; i < 8; ++i) {
            float4 s = *reinterpret_cast<const float4*>(&s_lds[buf][4 * lane + 256 * i]);
            sp[2 * i]     = (f32x2){s.x, s.y};
            sp[2 * i + 1] = (f32x2){s.z, s.w};
        }

        // ---- packed dots: v_pk_fma_f32, 2 MACs/instr, 4 rows in flight ----
        f32x2 acc2[ROWS_PER_WAVE];
        #pragma unroll
        for (int k = 0; k < ROWS_PER_WAVE; ++k) {
            f32x2 a = (f32x2){0.0f, 0.0f};
            #pragma unroll
            for (int i = 0; i < 4; ++i)
                a = __builtin_elementwise_fma(wi2[k][i], xv[i], a);
            #pragma unroll
            for (int i = 0; i < 16; ++i)
                a = __builtin_elementwise_fma(wr2[k][i], sp[i], a);
            acc2[k] = a;
        }

        // ---- horizontal + full-wave butterfly reduce (4 rows in flight) ----
        float acc[ROWS_PER_WAVE];
        #pragma unroll
        for (int k = 0; k < ROWS_PER_WAVE; ++k) acc[k] = acc2[k].x + acc2[k].y;
        #pragma unroll
        for (int off = 32; off > 0; off >>= 1) {
            #pragma unroll
            for (int k = 0; k < ROWS_PER_WAVE; ++k)
                acc[k] += __shfl_xor(acc[k], off, 64);
        }

        // ---- finalize: one 16B publish (lane 0), out store off-path (lane 2) ----
        const float v0 = fast_tanh(acc[0]) * INV_SQRT_N;
        const float v1 = fast_tanh(acc[1]) * INV_SQRT_N;
        const float v2 = fast_tanh(acc[2]) * INV_SQRT_N;
        const float v3 = fast_tanh(acc[3]) * INV_SQRT_N;
        const int   slotn = (t + 1) & 1;
        const float phin  = (((t + 1) >> 1) & 1) ? -1.0f : 1.0f;
        if (lane == 0) {
            f32x4 pk = {phin * (v0 + ENC_OFF), phin * (v1 + ENC_OFF),
                        phin * (v2 + ENC_OFF), phin * (v3 + ENC_OFF)};
            store_f4_coh(ring + (slotn << 11) + r0, pk);
        } else if (lane == 2) {
            // per-wave out store (rows r0..r0+3) — lane-scoped
            *reinterpret_cast<float4*>(out + (size_t)(t + 1) * N_RES + r0) =
                make_float4(v0, v1, v2, v3);
        }

        // ---- pin weights across the back edge (defeats reload/remat) ----
        #pragma unroll
        for (int k = 0; k < ROWS_PER_WAVE; ++k) {
            #pragma unroll
            for (int i = 0; i < 16; ++i) KEEP2(wr2[k][i]);
            #pragma unroll
            for (int i = 0; i < 4; ++i)  KEEP2(wi2[k][i]);
        }

        #pragma unroll
        for (int i = 0; i < 4; ++i) xv[i] = xn[i];
    }
}

extern "C" void kernel_launch(void* const* d_in, const int* in_sizes, int n_in,
                              void* d_out, int out_size, void* d_ws, size_t ws_size,
                              hipStream_t stream) {
    const float* input  = (const float*)d_in[0];
    const float* state0 = (const float*)d_in[1];
    const float* W_in   = (const float*)d_in[2];
    const float* W_res  = (const float*)d_in[3];
    float* out  = (float*)d_out;
    float* ring = (float*)d_ws;

    // zero = "not ready" for both phases; re-cleared on every call/replay
    hipMemsetAsync(d_ws, 0, 2 * N_RES * sizeof(float), stream);

    void* args[] = { (void*)&input, (void*)&state0, (void*)&W_in, (void*)&W_res,
                     (void*)&out, (void*)&ring };
    hipLaunchCooperativeKernel((const void*)reservoir_v11,
                               dim3(G_BLOCKS), dim3(B_THREADS),
                               args, 0, stream);
}